// Round 4
// baseline (2559.722 us; speedup 1.0000x reference)
//
#include <hip/hip_runtime.h>
#include <hip/hip_bf16.h>

#define N_ROWS 100000
#define IN_C   128
#define OUT_C  64
#define S_SC   3
#define NNZ_E  1600000
#define NNZ_F  1600000

// ---------------------------------------------------------------------------
// Kernel A: filtered[row, 0:64] += v * W[col, 0:64]
// One nnz per wave; 64 lanes = 64 output channels. W staged in LDS (fp32).
// ---------------------------------------------------------------------------
__global__ __launch_bounds__(256)
void feat_spmm(const int* __restrict__ fidx,
               const float* __restrict__ fval,
               const float* __restrict__ W,
               float* __restrict__ filtered)
{
    __shared__ float Wl[IN_C * OUT_C];
    for (int i = threadIdx.x; i < IN_C * OUT_C; i += blockDim.x)
        Wl[i] = W[i];
    __syncthreads();

    const int lane   = threadIdx.x & 63;
    const int wave   = blockIdx.x * 4 + (threadIdx.x >> 6);
    const int nwaves = gridDim.x * 4;

    for (int e = wave; e < NNZ_F; e += nwaves) {
        const int   row = fidx[e];             // wave-uniform (broadcast load)
        const int   col = fidx[NNZ_F + e];
        const float v   = fval[e];
        atomicAdd(&filtered[row * OUT_C + lane], v * Wl[col * OUT_C + lane]);
    }
}

// ---------------------------------------------------------------------------
// Kernel B: z[row, 0:64] += theta[row] * v * filtered[col, 0:64]
// (theta folded at production: z' = theta ⊙ (PhiInv @ filtered))
// ---------------------------------------------------------------------------
__global__ __launch_bounds__(256)
void spmm_scatter_theta(const int* __restrict__ rows,
                        const int* __restrict__ cols,
                        const float* __restrict__ vals,
                        const float* __restrict__ theta,
                        const float* __restrict__ src,
                        float* __restrict__ dst)
{
    const int lane   = threadIdx.x & 63;
    const int wave   = blockIdx.x * 4 + (threadIdx.x >> 6);
    const int nwaves = gridDim.x * 4;

    for (int e = wave; e < NNZ_E; e += nwaves) {
        const int r = rows[e];
        const int c = cols[e];
        const float v = vals[e] * theta[r];
        atomicAdd(&dst[r * OUT_C + lane], v * src[c * OUT_C + lane]);
    }
}

// ---------------------------------------------------------------------------
// Kernel C: dst[row, 0:64] += v * src[col, 0:64]   (plain scatter-SPMM)
// ---------------------------------------------------------------------------
__global__ __launch_bounds__(256)
void spmm_scatter(const int* __restrict__ rows,
                  const int* __restrict__ cols,
                  const float* __restrict__ vals,
                  const float* __restrict__ src,
                  float* __restrict__ dst)
{
    const int lane   = threadIdx.x & 63;
    const int wave   = blockIdx.x * 4 + (threadIdx.x >> 6);
    const int nwaves = gridDim.x * 4;

    for (int e = wave; e < NNZ_E; e += nwaves) {
        const int r = rows[e];
        const int c = cols[e];
        const float v = vals[e];
        atomicAdd(&dst[r * OUT_C + lane], v * src[c * OUT_C + lane]);
    }
}

// ---------------------------------------------------------------------------
// Kernel D: out[r, scale, 0:64] = relu(acc[r, 0:64])   (fp32 output!)
// ---------------------------------------------------------------------------
__global__ __launch_bounds__(256)
void relu_cast(const float* __restrict__ acc,
               float* __restrict__ out,
               int scale)
{
    const int t = blockIdx.x * blockDim.x + threadIdx.x;
    if (t >= N_ROWS * OUT_C) return;
    const int r = t >> 6;
    const int j = t & 63;
    float v = acc[t];
    v = v > 0.0f ? v : 0.0f;
    out[(r * S_SC + scale) * OUT_C + j] = v;
}

extern "C" void kernel_launch(void* const* d_in, const int* in_sizes, int n_in,
                              void* d_out, int out_size, void* d_ws, size_t ws_size,
                              hipStream_t stream)
{
    const int*   phi_idx  = (const int*)d_in[0];    // (S,2,NNZ) int32
    const float* phi_val  = (const float*)d_in[1];  // (S,NNZ)   fp32
    const int*   pinv_idx = (const int*)d_in[2];    // (S,2,NNZ) int32
    const float* pinv_val = (const float*)d_in[3];  // (S,NNZ)   fp32
    const int*   fidx     = (const int*)d_in[4];    // (2,NNZ_F) int32
    const float* fval     = (const float*)d_in[5];  // (NNZ_F,)  fp32
    const float* W        = (const float*)d_in[6];  // (128,64)  fp32
    const float* theta    = (const float*)d_in[7];  // (N,1)     fp32
    float*       out      = (float*)d_out;          // (N,S,64)  fp32

    const size_t MAT = (size_t)N_ROWS * OUT_C;  // 6.4M floats = 25.6 MB
    float* filtered = (float*)d_ws;             // [0, 25.6 MB)
    float* z        = filtered + MAT;           // [25.6, 51.2 MB)
    float* acc      = z + MAT;                  // [51.2, 76.8 MB)

    // ---- filtered = F @ W ----
    hipMemsetAsync(filtered, 0, MAT * sizeof(float), stream);
    feat_spmm<<<2048, 256, 0, stream>>>(fidx, fval, W, filtered);

    for (int i = 0; i < S_SC; ++i) {
        const int*   zr = pinv_idx + (size_t)(2 * i) * NNZ_E;     // rows
        const int*   zc = pinv_idx + (size_t)(2 * i + 1) * NNZ_E; // cols
        const float* zv = pinv_val + (size_t)i * NNZ_E;

        hipMemsetAsync(z, 0, MAT * sizeof(float), stream);
        spmm_scatter_theta<<<8192, 256, 0, stream>>>(zr, zc, zv, theta, filtered, z);

        const int*   orr = phi_idx + (size_t)(2 * i) * NNZ_E;
        const int*   oc  = phi_idx + (size_t)(2 * i + 1) * NNZ_E;
        const float* ov  = phi_val + (size_t)i * NNZ_E;

        hipMemsetAsync(acc, 0, MAT * sizeof(float), stream);
        spmm_scatter<<<8192, 256, 0, stream>>>(orr, oc, ov, z, acc);

        relu_cast<<<(int)((MAT + 255) / 256), 256, 0, stream>>>(acc, out, i);
    }
}

// Round 5
// 2329.301 us; speedup vs baseline: 1.0989x; 1.0989x over previous
//
#include <hip/hip_runtime.h>
#include <hip/hip_bf16.h>

#define N_ROWS 100000
#define IN_C   128
#define OUT_C  64
#define S_SC   3
#define NNZ    1600000
#define NMAT   7

#define SEG          512   // elements per scan block
#define BLKS_PER_MAT 196   // 196*512 = 100352 >= 100000

struct RowPtrs { const int* p[NMAT]; };

// ---------------------------------------------------------------------------
// 1) Histogram: counts[m][r] = #nnz with row r in matrix m  (all 7 at once)
// ---------------------------------------------------------------------------
__global__ __launch_bounds__(256)
void hist_all(RowPtrs P, int* __restrict__ counts)
{
    const int m = blockIdx.y;
    const int e = blockIdx.x * 256 + threadIdx.x;
    if (e < NNZ) atomicAdd(&counts[m * N_ROWS + P.p[m][e]], 1);
}

// ---------------------------------------------------------------------------
// 2a) Level-1 segmented exclusive scan: per 512-block scan + block totals
// ---------------------------------------------------------------------------
__global__ __launch_bounds__(256)
void scan_l1(const int* __restrict__ counts, int* __restrict__ row_start,
             int* __restrict__ bsum)
{
    __shared__ int buf[2][SEG];
    const int m   = blockIdx.y;
    const int blk = blockIdx.x;
    const int t   = threadIdx.x;

    for (int k = t; k < SEG; k += 256) {
        const int g = blk * SEG + k;
        buf[0][k] = (g < N_ROWS) ? counts[m * N_ROWS + g] : 0;
    }
    __syncthreads();

    int src = 0;
    for (int off = 1; off < SEG; off <<= 1) {
        for (int k = t; k < SEG; k += 256) {
            int v = buf[src][k];
            if (k >= off) v += buf[src][k - off];
            buf[1 - src][k] = v;
        }
        src ^= 1;
        __syncthreads();
    }
    // buf[src] = inclusive scan; write exclusive
    for (int k = t; k < SEG; k += 256) {
        const int g = blk * SEG + k;
        if (g < N_ROWS)
            row_start[m * N_ROWS + g] = (k == 0) ? 0 : buf[src][k - 1];
    }
    if (t == 0) bsum[m * BLKS_PER_MAT + blk] = buf[src][SEG - 1];
}

// ---------------------------------------------------------------------------
// 2b) Level-2: exclusive scan of the 196 block sums, per matrix (one block)
// ---------------------------------------------------------------------------
__global__ __launch_bounds__(256)
void scan_l2(int* __restrict__ bsum)
{
    __shared__ int buf[2][256];
    const int t = threadIdx.x;
    for (int m = 0; m < NMAT; ++m) {
        buf[0][t] = (t < BLKS_PER_MAT) ? bsum[m * BLKS_PER_MAT + t] : 0;
        __syncthreads();
        int src = 0;
        for (int off = 1; off < 256; off <<= 1) {
            int v = buf[src][t];
            if (t >= off) v += buf[src][t - off];
            buf[1 - src][t] = v;
            src ^= 1;
            __syncthreads();
        }
        if (t < BLKS_PER_MAT)
            bsum[m * BLKS_PER_MAT + t] = (t == 0) ? 0 : buf[src][t - 1];
        __syncthreads();
    }
}

// ---------------------------------------------------------------------------
// 2c) Add block offsets; initialize fill cursors
// ---------------------------------------------------------------------------
__global__ __launch_bounds__(256)
void add_offs(const int* __restrict__ bsum, int* __restrict__ row_start,
              int* __restrict__ cursor)
{
    const int i = blockIdx.x * 256 + threadIdx.x;
    if (i >= NMAT * N_ROWS) return;
    const int m   = i / N_ROWS;
    const int pos = i - m * N_ROWS;
    const int v = row_start[i] + bsum[m * BLKS_PER_MAT + pos / SEG];
    row_start[i] = v;
    cursor[i]    = v;
}

// ---------------------------------------------------------------------------
// 3) Fill permutation: perm[pos] = nnz index, grouped by row
// ---------------------------------------------------------------------------
__global__ __launch_bounds__(256)
void fill_perm(const int* __restrict__ rows, int* __restrict__ cursor,
               int* __restrict__ perm)
{
    const int e = blockIdx.x * 256 + threadIdx.x;
    if (e < NNZ) {
        const int pos = atomicAdd(&cursor[rows[e]], 1);
        perm[pos] = e;
    }
}

// ---------------------------------------------------------------------------
// 4a) Gather-SPMM vs LDS-cached W: filtered[r] = sum v * W[c]
// ---------------------------------------------------------------------------
__global__ __launch_bounds__(256)
void gather_W(const int* __restrict__ start, const int* __restrict__ end,
              const int* __restrict__ perm, const int* __restrict__ cols,
              const float* __restrict__ vals, const float* __restrict__ W,
              float* __restrict__ dst)
{
    __shared__ float Wl[IN_C * OUT_C];
    for (int i = threadIdx.x; i < IN_C * OUT_C; i += blockDim.x) Wl[i] = W[i];
    __syncthreads();

    const int lane = threadIdx.x & 63;
    const int wave = blockIdx.x * 4 + (threadIdx.x >> 6);
    const int nw   = gridDim.x * 4;

    for (int r = wave; r < N_ROWS; r += nw) {
        const int s = start[r], t = end[r];
        float acc = 0.0f;
        for (int base = s; base < t; base += 64) {
            const int k = min(64, t - base);
            int c = 0; float v = 0.0f;
            if (lane < k) {
                const int e = perm[base + lane];
                c = cols[e]; v = vals[e];
            }
            for (int j = 0; j < k; ++j) {
                const int   cc = __shfl(c, j);
                const float vv = __shfl(v, j);
                acc += vv * Wl[cc * OUT_C + lane];
            }
        }
        dst[r * OUT_C + lane] = acc;
    }
}

// ---------------------------------------------------------------------------
// 4b) Gather-SPMM from global src.
// MODE 1: dst[r] = theta[r] * sum v*src[c]          (z production)
// MODE 2: out[(r*3+scale)] = relu(sum v*src[c])     (final output)
// ---------------------------------------------------------------------------
template <int MODE>
__global__ __launch_bounds__(256)
void gather_mat(const int* __restrict__ start, const int* __restrict__ end,
                const int* __restrict__ perm, const int* __restrict__ cols,
                const float* __restrict__ vals, const float* __restrict__ theta,
                const float* __restrict__ src, float* __restrict__ dst,
                int scale)
{
    const int lane = threadIdx.x & 63;
    const int wave = blockIdx.x * 4 + (threadIdx.x >> 6);
    const int nw   = gridDim.x * 4;

    for (int r = wave; r < N_ROWS; r += nw) {
        const int s = start[r], t = end[r];
        float acc = 0.0f;
        for (int base = s; base < t; base += 64) {
            const int k = min(64, t - base);
            int c = 0; float v = 0.0f;
            if (lane < k) {
                const int e = perm[base + lane];
                c = cols[e]; v = vals[e];
            }
            for (int j = 0; j < k; ++j) {
                const int   cc = __shfl(c, j);
                const float vv = __shfl(v, j);
                acc += vv * src[cc * OUT_C + lane];
            }
        }
        if (MODE == 1) {
            dst[r * OUT_C + lane] = theta[r] * acc;
        } else {
            dst[(r * S_SC + scale) * OUT_C + lane] = acc > 0.0f ? acc : 0.0f;
        }
    }
}

extern "C" void kernel_launch(void* const* d_in, const int* in_sizes, int n_in,
                              void* d_out, int out_size, void* d_ws, size_t ws_size,
                              hipStream_t stream)
{
    const int*   phi_idx  = (const int*)d_in[0];    // (S,2,NNZ) int32
    const float* phi_val  = (const float*)d_in[1];  // (S,NNZ)   fp32
    const int*   pinv_idx = (const int*)d_in[2];    // (S,2,NNZ) int32
    const float* pinv_val = (const float*)d_in[3];  // (S,NNZ)   fp32
    const int*   fidx     = (const int*)d_in[4];    // (2,NNZ)   int32
    const float* fval     = (const float*)d_in[5];  // (NNZ,)    fp32
    const float* W        = (const float*)d_in[6];  // (128,64)  fp32
    const float* theta    = (const float*)d_in[7];  // (N,1)     fp32
    float*       out      = (float*)d_out;          // (N,S,64)  fp32

    // ---- workspace layout (66 MB total; 76.8 MB proven available) ----
    float* filtered  = (float*)d_ws;                 // 6.4M fp32
    float* z         = filtered + (size_t)N_ROWS * OUT_C;
    int*   counts    = (int*)(z + (size_t)N_ROWS * OUT_C);
    int*   row_start = counts + NMAT * N_ROWS;
    int*   cursor    = row_start + NMAT * N_ROWS;
    int*   bsum      = cursor + NMAT * N_ROWS;       // 1372 used, 2048 reserved
    int*   perm      = bsum + 2048;                  // 1.6M ints (reused x7)

    // matrix order: 0=F, then per scale i: 1+2i=PhiInv_i, 2+2i=Phi_i
    RowPtrs P;
    P.p[0] = fidx;
    for (int i = 0; i < S_SC; ++i) {
        P.p[1 + 2 * i] = pinv_idx + (size_t)(2 * i) * NNZ;
        P.p[2 + 2 * i] = phi_idx  + (size_t)(2 * i) * NNZ;
    }

    // ---- CSR build (all 7 matrices) ----
    hipMemsetAsync(counts, 0, NMAT * N_ROWS * sizeof(int), stream);
    hist_all<<<dim3(NNZ / 256, NMAT), 256, 0, stream>>>(P, counts);
    scan_l1<<<dim3(BLKS_PER_MAT, NMAT), 256, 0, stream>>>(counts, row_start, bsum);
    scan_l2<<<1, 256, 0, stream>>>(bsum);
    add_offs<<<(NMAT * N_ROWS + 255) / 256, 256, 0, stream>>>(bsum, row_start, cursor);

    // ---- m=0: filtered = F @ W ----
    fill_perm<<<NNZ / 256, 256, 0, stream>>>(P.p[0], cursor, perm);
    gather_W<<<1024, 256, 0, stream>>>(row_start, cursor, perm,
                                       fidx + NNZ, fval, W, filtered);

    for (int i = 0; i < S_SC; ++i) {
        const int m1 = 1 + 2 * i, m2 = 2 + 2 * i;
        const int*   zc = pinv_idx + (size_t)(2 * i + 1) * NNZ;
        const float* zv = pinv_val + (size_t)i * NNZ;
        const int*   oc = phi_idx  + (size_t)(2 * i + 1) * NNZ;
        const float* ov = phi_val  + (size_t)i * NNZ;

        // z = theta ⊙ (PhiInv_i @ filtered)
        fill_perm<<<NNZ / 256, 256, 0, stream>>>(P.p[m1], cursor + m1 * N_ROWS, perm);
        gather_mat<1><<<4096, 256, 0, stream>>>(row_start + m1 * N_ROWS,
                                                cursor + m1 * N_ROWS, perm,
                                                zc, zv, theta, filtered, z, 0);

        // out[:, i, :] = relu(Phi_i @ z)
        fill_perm<<<NNZ / 256, 256, 0, stream>>>(P.p[m2], cursor + m2 * N_ROWS, perm);
        gather_mat<2><<<4096, 256, 0, stream>>>(row_start + m2 * N_ROWS,
                                                cursor + m2 * N_ROWS, perm,
                                                oc, ov, nullptr, z, out, i);
    }
}

// Round 6
// 2092.528 us; speedup vs baseline: 1.2233x; 1.1132x over previous
//
#include <hip/hip_runtime.h>
#include <hip/hip_bf16.h>

#define N_ROWS 100000
#define IN_C   128
#define OUT_C  64
#define S_SC   3
#define NNZ    1600000
#define NCOL   8      // color-privatized counter copies (~XCDs)

#define SEG          512
#define BLKS_SCAN    196   // 196*512 = 100352 >= 100000

// ---------------------------------------------------------------------------
// 1) Colored histogram: counts8[color][r] += 1, color = blockIdx & 7.
//    If blocks round-robin across XCDs, each copy is XCD-local -> L2 atomics.
// ---------------------------------------------------------------------------
__global__ __launch_bounds__(256)
void hist8(const int* __restrict__ rows, int* __restrict__ counts8)
{
    const int e = blockIdx.x * 256 + threadIdx.x;
    const int color = blockIdx.x & (NCOL - 1);
    if (e < NNZ) atomicAdd(&counts8[color * N_ROWS + rows[e]], 1);
}

// ---------------------------------------------------------------------------
// 2a) Per-512-row block scan of totals (sum over colors) + block sums
// ---------------------------------------------------------------------------
__global__ __launch_bounds__(256)
void scan_l1(const int* __restrict__ counts8, int* __restrict__ row_start,
             int* __restrict__ bsum)
{
    __shared__ int buf[2][SEG];
    const int blk = blockIdx.x;
    const int t   = threadIdx.x;

    for (int k = t; k < SEG; k += 256) {
        const int g = blk * SEG + k;
        int tot = 0;
        if (g < N_ROWS)
            for (int c = 0; c < NCOL; ++c) tot += counts8[c * N_ROWS + g];
        buf[0][k] = tot;
    }
    __syncthreads();

    int src = 0;
    for (int off = 1; off < SEG; off <<= 1) {
        for (int k = t; k < SEG; k += 256) {
            int v = buf[src][k];
            if (k >= off) v += buf[src][k - off];
            buf[1 - src][k] = v;
        }
        src ^= 1;
        __syncthreads();
    }
    for (int k = t; k < SEG; k += 256) {
        const int g = blk * SEG + k;
        if (g < N_ROWS)
            row_start[g] = (k == 0) ? 0 : buf[src][k - 1];   // block-local excl
    }
    if (t == 0) bsum[blk] = buf[src][SEG - 1];
}

// ---------------------------------------------------------------------------
// 2b) Exclusive scan of the 196 block sums (single block)
// ---------------------------------------------------------------------------
__global__ __launch_bounds__(256)
void scan_l2(int* __restrict__ bsum)
{
    __shared__ int buf[2][256];
    const int t = threadIdx.x;
    buf[0][t] = (t < BLKS_SCAN) ? bsum[t] : 0;
    __syncthreads();
    int src = 0;
    for (int off = 1; off < 256; off <<= 1) {
        int v = buf[src][t];
        if (t >= off) v += buf[src][t - off];
        buf[1 - src][t] = v;
        src ^= 1;
        __syncthreads();
    }
    if (t < BLKS_SCAN) bsum[t] = (t == 0) ? 0 : buf[src][t - 1];
}

// ---------------------------------------------------------------------------
// 2c) Finalize: absolute row_start/row_end; convert counts8 -> per-color
//     cursors (in place), laid out [start + sum of earlier colors' counts).
// ---------------------------------------------------------------------------
__global__ __launch_bounds__(256)
void finalize(const int* __restrict__ bsum, int* __restrict__ row_start,
              int* __restrict__ row_end, int* __restrict__ counts8)
{
    const int r = blockIdx.x * 256 + threadIdx.x;
    if (r >= N_ROWS) return;
    const int base = row_start[r] + bsum[r / SEG];
    row_start[r] = base;
    int running = base;
    for (int c = 0; c < NCOL; ++c) {
        const int cnt = counts8[c * N_ROWS + r];
        counts8[c * N_ROWS + r] = running;    // becomes cursor
        running += cnt;
    }
    row_end[r] = running;
}

// ---------------------------------------------------------------------------
// 3) Colored fill: write (col, val) grouped by row, color-local cursors
// ---------------------------------------------------------------------------
__global__ __launch_bounds__(256)
void fill8(const int* __restrict__ rows, const int* __restrict__ cols,
           const float* __restrict__ vals, int* __restrict__ cur8,
           int* __restrict__ sorted_col, float* __restrict__ sorted_val)
{
    const int e = blockIdx.x * 256 + threadIdx.x;
    const int color = blockIdx.x & (NCOL - 1);
    if (e < NNZ) {
        const int pos = atomicAdd(&cur8[color * N_ROWS + rows[e]], 1);
        sorted_col[pos] = cols[e];
        sorted_val[pos] = vals[e];
    }
}

// ---------------------------------------------------------------------------
// 4a) Gather-SPMM vs LDS-cached W: filtered[r] = sum v * W[c]
// ---------------------------------------------------------------------------
__global__ __launch_bounds__(256)
void gather_W(const int* __restrict__ start, const int* __restrict__ end,
              const int* __restrict__ scol, const float* __restrict__ sval,
              const float* __restrict__ W, float* __restrict__ dst)
{
    __shared__ float Wl[IN_C * OUT_C];
    for (int i = threadIdx.x; i < IN_C * OUT_C; i += blockDim.x) Wl[i] = W[i];
    __syncthreads();

    const int lane = threadIdx.x & 63;
    const int wave = blockIdx.x * 4 + (threadIdx.x >> 6);
    const int nw   = gridDim.x * 4;

    for (int r = wave; r < N_ROWS; r += nw) {
        const int s = start[r], t = end[r];
        float acc = 0.0f;
        for (int base = s; base < t; base += 64) {
            const int k = min(64, t - base);
            int c = 0; float v = 0.0f;
            if (lane < k) { c = scol[base + lane]; v = sval[base + lane]; }
            for (int j = 0; j < k; ++j) {
                const int   cc = __shfl(c, j);
                const float vv = __shfl(v, j);
                acc += vv * Wl[cc * OUT_C + lane];
            }
        }
        dst[r * OUT_C + lane] = acc;
    }
}

// ---------------------------------------------------------------------------
// 4b) Gather-SPMM from global src.
// MODE 1: dst[r] = theta[r] * sum v*src[c]          (z production)
// MODE 2: out[(r*3+scale)] = relu(sum v*src[c])     (final output)
// ---------------------------------------------------------------------------
template <int MODE>
__global__ __launch_bounds__(256)
void gather_mat(const int* __restrict__ start, const int* __restrict__ end,
                const int* __restrict__ scol, const float* __restrict__ sval,
                const float* __restrict__ theta, const float* __restrict__ src,
                float* __restrict__ dst, int scale)
{
    const int lane = threadIdx.x & 63;
    const int wave = blockIdx.x * 4 + (threadIdx.x >> 6);
    const int nw   = gridDim.x * 4;

    for (int r = wave; r < N_ROWS; r += nw) {
        const int s = start[r], t = end[r];
        float acc = 0.0f;
        for (int base = s; base < t; base += 64) {
            const int k = min(64, t - base);
            int c = 0; float v = 0.0f;
            if (lane < k) { c = scol[base + lane]; v = sval[base + lane]; }
            for (int j = 0; j < k; ++j) {
                const int   cc = __shfl(c, j);
                const float vv = __shfl(v, j);
                acc += vv * src[cc * OUT_C + lane];
            }
        }
        if (MODE == 1) {
            dst[r * OUT_C + lane] = theta[r] * acc;
        } else {
            dst[(r * S_SC + scale) * OUT_C + lane] = acc > 0.0f ? acc : 0.0f;
        }
    }
}

// ---------------------------------------------------------------------------
static void build_csr(const int* rows, int* counts8, int* row_start,
                      int* row_end, int* bsum, hipStream_t stream)
{
    hipMemsetAsync(counts8, 0, NCOL * N_ROWS * sizeof(int), stream);
    hist8<<<NNZ / 256, 256, 0, stream>>>(rows, counts8);
    scan_l1<<<BLKS_SCAN, 256, 0, stream>>>(counts8, row_start, bsum);
    scan_l2<<<1, 256, 0, stream>>>(bsum);
    finalize<<<(N_ROWS + 255) / 256, 256, 0, stream>>>(bsum, row_start,
                                                       row_end, counts8);
}

extern "C" void kernel_launch(void* const* d_in, const int* in_sizes, int n_in,
                              void* d_out, int out_size, void* d_ws, size_t ws_size,
                              hipStream_t stream)
{
    const int*   phi_idx  = (const int*)d_in[0];    // (S,2,NNZ) int32
    const float* phi_val  = (const float*)d_in[1];  // (S,NNZ)   fp32
    const int*   pinv_idx = (const int*)d_in[2];    // (S,2,NNZ) int32
    const float* pinv_val = (const float*)d_in[3];  // (S,NNZ)   fp32
    const int*   fidx     = (const int*)d_in[4];    // (2,NNZ)   int32
    const float* fval     = (const float*)d_in[5];  // (NNZ,)    fp32
    const float* W        = (const float*)d_in[6];  // (128,64)  fp32
    const float* theta    = (const float*)d_in[7];  // (N,1)     fp32
    float*       out      = (float*)d_out;          // (N,S,64)  fp32

    // ---- workspace (≈68 MB; 76.8 MB proven available) ----
    float* filtered   = (float*)d_ws;                       // 25.6 MB
    float* z          = filtered + (size_t)N_ROWS * OUT_C;  // 25.6 MB
    int*   counts8    = (int*)(z + (size_t)N_ROWS * OUT_C); // 3.2 MB
    int*   row_start  = counts8 + NCOL * N_ROWS;            // 0.4 MB
    int*   row_end    = row_start + N_ROWS;                 // 0.4 MB
    int*   bsum       = row_end + N_ROWS;                   // 256 ints
    int*   sorted_col = bsum + 256;                         // 6.4 MB
    float* sorted_val = (float*)(sorted_col + NNZ);         // 6.4 MB

    // ---- filtered = F @ W ----
    build_csr(fidx, counts8, row_start, row_end, bsum, stream);
    fill8<<<NNZ / 256, 256, 0, stream>>>(fidx, fidx + NNZ, fval, counts8,
                                         sorted_col, sorted_val);
    gather_W<<<2048, 256, 0, stream>>>(row_start, row_end, sorted_col,
                                       sorted_val, W, filtered);

    for (int i = 0; i < S_SC; ++i) {
        const int*   zr = pinv_idx + (size_t)(2 * i) * NNZ;
        const int*   zc = pinv_idx + (size_t)(2 * i + 1) * NNZ;
        const float* zv = pinv_val + (size_t)i * NNZ;
        const int*   orr = phi_idx + (size_t)(2 * i) * NNZ;
        const int*   oc  = phi_idx + (size_t)(2 * i + 1) * NNZ;
        const float* ov  = phi_val + (size_t)i * NNZ;

        // z = theta ⊙ (PhiInv_i @ filtered)
        build_csr(zr, counts8, row_start, row_end, bsum, stream);
        fill8<<<NNZ / 256, 256, 0, stream>>>(zr, zc, zv, counts8,
                                             sorted_col, sorted_val);
        gather_mat<1><<<4096, 256, 0, stream>>>(row_start, row_end, sorted_col,
                                                sorted_val, theta, filtered, z, 0);

        // out[:, i, :] = relu(Phi_i @ z)
        build_csr(orr, counts8, row_start, row_end, bsum, stream);
        fill8<<<NNZ / 256, 256, 0, stream>>>(orr, oc, ov, counts8,
                                             sorted_col, sorted_val);
        gather_mat<2><<<4096, 256, 0, stream>>>(row_start, row_end, sorted_col,
                                                sorted_val, nullptr, z, out, i);
    }
}

// Round 7
// 1711.897 us; speedup vs baseline: 1.4953x; 1.2223x over previous
//
#include <hip/hip_runtime.h>
#include <hip/hip_bf16.h>

#define N_ROWS 100000
#define IN_C   128
#define OUT_C  64
#define S_SC   3
#define NNZ    1600000
#define NMAT   7
#define NCOL   8      // color-privatized counter copies (~XCDs)

#define SEG       512
#define BLKS_SCAN 196   // 196*512 = 100352 >= 100000

struct RowPtrs { const int* p[NMAT]; };

__device__ __forceinline__ float bf2f(__hip_bfloat16 x) { return __bfloat162float(x); }

// ---------------------------------------------------------------------------
// 1) Colored histogram, all 7 matrices: counts8[(m*NCOL+color)][r] += 1
// ---------------------------------------------------------------------------
__global__ __launch_bounds__(256)
void hist_all(RowPtrs P, int* __restrict__ counts8)
{
    const int m = blockIdx.y;
    const int e = blockIdx.x * 256 + threadIdx.x;
    const int color = blockIdx.x & (NCOL - 1);
    if (e < NNZ)
        atomicAdd(&counts8[((size_t)m * NCOL + color) * N_ROWS + P.p[m][e]], 1);
}

// ---------------------------------------------------------------------------
// 2a) Per-512-row block scan of totals (sum over colors) + block sums
// ---------------------------------------------------------------------------
__global__ __launch_bounds__(256)
void scan_l1(const int* __restrict__ counts8, int* __restrict__ row_start,
             int* __restrict__ bsum)
{
    __shared__ int buf[2][SEG];
    const int m   = blockIdx.y;
    const int blk = blockIdx.x;
    const int t   = threadIdx.x;
    const int* cnt = counts8 + (size_t)m * NCOL * N_ROWS;

    for (int k = t; k < SEG; k += 256) {
        const int g = blk * SEG + k;
        int tot = 0;
        if (g < N_ROWS)
            for (int c = 0; c < NCOL; ++c) tot += cnt[c * N_ROWS + g];
        buf[0][k] = tot;
    }
    __syncthreads();

    int src = 0;
    for (int off = 1; off < SEG; off <<= 1) {
        for (int k = t; k < SEG; k += 256) {
            int v = buf[src][k];
            if (k >= off) v += buf[src][k - off];
            buf[1 - src][k] = v;
        }
        src ^= 1;
        __syncthreads();
    }
    for (int k = t; k < SEG; k += 256) {
        const int g = blk * SEG + k;
        if (g < N_ROWS)
            row_start[m * N_ROWS + g] = (k == 0) ? 0 : buf[src][k - 1];
    }
    if (t == 0) bsum[m * 256 + blk] = buf[src][SEG - 1];
}

// ---------------------------------------------------------------------------
// 2b) Exclusive scan of block sums; one block per matrix
// ---------------------------------------------------------------------------
__global__ __launch_bounds__(256)
void scan_l2(int* __restrict__ bsum)
{
    __shared__ int buf[2][256];
    const int t = threadIdx.x;
    int* b = bsum + blockIdx.x * 256;
    buf[0][t] = (t < BLKS_SCAN) ? b[t] : 0;
    __syncthreads();
    int src = 0;
    for (int off = 1; off < 256; off <<= 1) {
        int v = buf[src][t];
        if (t >= off) v += buf[src][t - off];
        buf[1 - src][t] = v;
        src ^= 1;
        __syncthreads();
    }
    if (t < BLKS_SCAN) b[t] = (t == 0) ? 0 : buf[src][t - 1];
}

// ---------------------------------------------------------------------------
// 2c) Finalize: absolute row_start/row_end; counts8 -> per-color cursors
// ---------------------------------------------------------------------------
__global__ __launch_bounds__(256)
void finalize(const int* __restrict__ bsum, int* __restrict__ row_start,
              int* __restrict__ row_end, int* __restrict__ counts8)
{
    const int i = blockIdx.x * 256 + threadIdx.x;
    if (i >= NMAT * N_ROWS) return;
    const int m = i / N_ROWS;
    const int r = i - m * N_ROWS;
    int* cnt = counts8 + (size_t)m * NCOL * N_ROWS;
    const int base = row_start[i] + bsum[m * 256 + r / SEG];
    row_start[i] = base;
    int running = base;
    for (int c = 0; c < NCOL; ++c) {
        const int v = cnt[c * N_ROWS + r];
        cnt[c * N_ROWS + r] = running;      // becomes cursor
        running += v;
    }
    row_end[i] = running;
}

// ---------------------------------------------------------------------------
// 3) Colored fill: one packed 8B (col,val) store per nnz
// ---------------------------------------------------------------------------
__global__ __launch_bounds__(256)
void fill8(const int* __restrict__ rows, const int* __restrict__ cols,
           const float* __restrict__ vals, int* __restrict__ cur8,
           uint2* __restrict__ scv)
{
    const int e = blockIdx.x * 256 + threadIdx.x;
    const int color = blockIdx.x & (NCOL - 1);
    if (e < NNZ) {
        const int pos = atomicAdd(&cur8[color * N_ROWS + rows[e]], 1);
        scv[pos] = make_uint2((unsigned)cols[e], __float_as_uint(vals[e]));
    }
}

// ---------------------------------------------------------------------------
// 4a) Gather-SPMM vs LDS W (fp32): filtered[r] = bf16(sum v * W[c])
// ---------------------------------------------------------------------------
__global__ __launch_bounds__(256)
void gather_W(const int* __restrict__ start, const int* __restrict__ end,
              const uint2* __restrict__ scv, const float* __restrict__ W,
              __hip_bfloat16* __restrict__ dst)
{
    __shared__ float Wl[IN_C * OUT_C];
    for (int i = threadIdx.x; i < IN_C * OUT_C; i += blockDim.x) Wl[i] = W[i];
    __syncthreads();

    const int lane = threadIdx.x & 63;
    const int wave = blockIdx.x * 4 + (threadIdx.x >> 6);
    const int nw   = gridDim.x * 4;

    for (int r = wave; r < N_ROWS; r += nw) {
        const int s = start[r], t = end[r];
        float a0 = 0.f, a1 = 0.f, a2 = 0.f, a3 = 0.f;
        int j = s;
        for (; j + 3 < t; j += 4) {
            const uint2 p0 = scv[j],     p1 = scv[j + 1];
            const uint2 p2 = scv[j + 2], p3 = scv[j + 3];
            a0 += __uint_as_float(p0.y) * Wl[p0.x * OUT_C + lane];
            a1 += __uint_as_float(p1.y) * Wl[p1.x * OUT_C + lane];
            a2 += __uint_as_float(p2.y) * Wl[p2.x * OUT_C + lane];
            a3 += __uint_as_float(p3.y) * Wl[p3.x * OUT_C + lane];
        }
        for (; j < t; ++j) {
            const uint2 p = scv[j];
            a0 += __uint_as_float(p.y) * Wl[p.x * OUT_C + lane];
        }
        dst[r * OUT_C + lane] = __float2bfloat16((a0 + a1) + (a2 + a3));
    }
}

// ---------------------------------------------------------------------------
// 4b) Gather-SPMM from bf16 src (wave-uniform pair loads, x4 unroll).
// MODE 1: dst[r] = bf16(theta[r] * sum v*src[c])
// MODE 2: out[(r*3+scale)] = relu(sum v*src[c])   (fp32)
// ---------------------------------------------------------------------------
template <int MODE>
__global__ __launch_bounds__(256)
void gather_mat(const int* __restrict__ start, const int* __restrict__ end,
                const uint2* __restrict__ scv,
                const __hip_bfloat16* __restrict__ src,
                const float* __restrict__ theta,
                __hip_bfloat16* __restrict__ dstb,
                float* __restrict__ dstf, int scale)
{
    const int lane = threadIdx.x & 63;
    const int wave = blockIdx.x * 4 + (threadIdx.x >> 6);
    const int nw   = gridDim.x * 4;

    for (int r = wave; r < N_ROWS; r += nw) {
        const int s = start[r], t = end[r];
        float a0 = 0.f, a1 = 0.f, a2 = 0.f, a3 = 0.f;
        int j = s;
        for (; j + 3 < t; j += 4) {
            const uint2 p0 = scv[j],     p1 = scv[j + 1];
            const uint2 p2 = scv[j + 2], p3 = scv[j + 3];
            const float w0 = bf2f(src[p0.x * OUT_C + lane]);
            const float w1 = bf2f(src[p1.x * OUT_C + lane]);
            const float w2 = bf2f(src[p2.x * OUT_C + lane]);
            const float w3 = bf2f(src[p3.x * OUT_C + lane]);
            a0 += __uint_as_float(p0.y) * w0;
            a1 += __uint_as_float(p1.y) * w1;
            a2 += __uint_as_float(p2.y) * w2;
            a3 += __uint_as_float(p3.y) * w3;
        }
        for (; j < t; ++j) {
            const uint2 p = scv[j];
            a0 += __uint_as_float(p.y) * bf2f(src[p.x * OUT_C + lane]);
        }
        const float acc = (a0 + a1) + (a2 + a3);
        if (MODE == 1) {
            dstb[r * OUT_C + lane] = __float2bfloat16(theta[r] * acc);
        } else {
            dstf[(r * S_SC + scale) * OUT_C + lane] = acc > 0.0f ? acc : 0.0f;
        }
    }
}

extern "C" void kernel_launch(void* const* d_in, const int* in_sizes, int n_in,
                              void* d_out, int out_size, void* d_ws, size_t ws_size,
                              hipStream_t stream)
{
    const int*   phi_idx  = (const int*)d_in[0];
    const float* phi_val  = (const float*)d_in[1];
    const int*   pinv_idx = (const int*)d_in[2];
    const float* pinv_val = (const float*)d_in[3];
    const int*   fidx     = (const int*)d_in[4];
    const float* fval     = (const float*)d_in[5];
    const float* W        = (const float*)d_in[6];
    const float* theta    = (const float*)d_in[7];
    float*       out      = (float*)d_out;          // (N,S,64) fp32

    // ---- workspace (≈66.3 MB; 76.8 MB proven) ----
    __hip_bfloat16* filtered = (__hip_bfloat16*)d_ws;                  // 12.8 MB
    __hip_bfloat16* z        = filtered + (size_t)N_ROWS * OUT_C;      // 12.8 MB
    int*   counts8   = (int*)(z + (size_t)N_ROWS * OUT_C);             // 22.4 MB
    int*   row_start = counts8 + (size_t)NMAT * NCOL * N_ROWS;         // 2.8 MB
    int*   row_end   = row_start + NMAT * N_ROWS;                      // 2.8 MB
    int*   bsum      = row_end + NMAT * N_ROWS;                        // 7 KB
    uint2* scv       = (uint2*)(bsum + NMAT * 256);                    // 12.8 MB

    // matrix order: 0=F, per scale i: 1+2i=PhiInv_i, 2+2i=Phi_i
    RowPtrs P;
    P.p[0] = fidx;
    for (int i = 0; i < S_SC; ++i) {
        P.p[1 + 2 * i] = pinv_idx + (size_t)(2 * i) * NNZ;
        P.p[2 + 2 * i] = phi_idx  + (size_t)(2 * i) * NNZ;
    }

    // ---- batched CSR metadata for all 7 matrices ----
    hipMemsetAsync(counts8, 0, (size_t)NMAT * NCOL * N_ROWS * sizeof(int), stream);
    hist_all<<<dim3(NNZ / 256, NMAT), 256, 0, stream>>>(P, counts8);
    scan_l1<<<dim3(BLKS_SCAN, NMAT), 256, 0, stream>>>(counts8, row_start, bsum);
    scan_l2<<<NMAT, 256, 0, stream>>>(bsum);
    finalize<<<(NMAT * N_ROWS + 255) / 256, 256, 0, stream>>>(bsum, row_start,
                                                              row_end, counts8);

    // ---- m=0: filtered = bf16(F @ W) ----
    fill8<<<NNZ / 256, 256, 0, stream>>>(fidx, fidx + NNZ, fval, counts8, scv);
    gather_W<<<2048, 256, 0, stream>>>(row_start, row_end, scv, W, filtered);

    for (int i = 0; i < S_SC; ++i) {
        const int m1 = 1 + 2 * i, m2 = 2 + 2 * i;
        const int*   zc = pinv_idx + (size_t)(2 * i + 1) * NNZ;
        const float* zv = pinv_val + (size_t)i * NNZ;
        const int*   oc = phi_idx  + (size_t)(2 * i + 1) * NNZ;
        const float* ov = phi_val  + (size_t)i * NNZ;

        // z = bf16(theta ⊙ (PhiInv_i @ filtered))
        fill8<<<NNZ / 256, 256, 0, stream>>>(P.p[m1], zc, zv,
                                             counts8 + (size_t)m1 * NCOL * N_ROWS, scv);
        gather_mat<1><<<4096, 256, 0, stream>>>(row_start + m1 * N_ROWS,
                                                row_end + m1 * N_ROWS, scv,
                                                filtered, theta, z, nullptr, 0);

        // out[:, i, :] = relu(Phi_i @ z)
        fill8<<<NNZ / 256, 256, 0, stream>>>(P.p[m2], oc, ov,
                                             counts8 + (size_t)m2 * NCOL * N_ROWS, scv);
        gather_mat<2><<<4096, 256, 0, stream>>>(row_start + m2 * N_ROWS,
                                                row_end + m2 * N_ROWS, scv,
                                                z, nullptr, nullptr, out, i);
    }
}